// Round 3
// baseline (1460.611 us; speedup 1.0000x reference)
//
#include <hip/hip_runtime.h>
#include <hip/hip_bf16.h>

#define D128 128

typedef __attribute__((ext_vector_type(8))) short bf16x8;
typedef __attribute__((ext_vector_type(4))) float f32x4;
typedef unsigned int uint;
typedef unsigned short ushort_t;

union U4 { uint4 u; bf16x8 h; };
__device__ __forceinline__ bf16x8 as_h(uint4 u) { U4 x; x.u = u; return x.h; }

__device__ __forceinline__ short f2bf(float f) {
  union { float f; unsigned u; } v; v.f = f;
  unsigned r = v.u + 0x7FFFu + ((v.u >> 16) & 1u);  // RNE
  return (short)(r >> 16);
}
__device__ __forceinline__ float bf_lo(uint v) {
  union { uint u; float f; } x; x.u = v << 16; return x.f;
}
__device__ __forceinline__ float bf_hi(uint v) {
  union { uint u; float f; } x; x.u = v & 0xFFFF0000u; return x.f;
}
__device__ __forceinline__ uint pack2(float a, float b) {
  return (uint)(unsigned short)f2bf(a) | ((uint)(unsigned short)f2bf(b) << 16);
}
__device__ __forceinline__ uint relu_pk2(uint v) {
  uint r = (v & 0x80000000u) ? (v & 0x0000FFFFu) : v;
  r = (r & 0x00008000u) ? (r & 0xFFFF0000u) : r;
  return r;
}

// ---- f32 -> bf16, 4 elements/thread ----
__global__ __launch_bounds__(256) void cvt4_k(const float* __restrict__ in,
                                              ushort_t* __restrict__ out, int n4) {
  int i = blockIdx.x * 256 + threadIdx.x;
  if (i >= n4) return;
  float4 v = ((const float4*)in)[i];
  ushort4 o;
  o.x = (unsigned short)f2bf(v.x); o.y = (unsigned short)f2bf(v.y);
  o.z = (unsigned short)f2bf(v.z); o.w = (unsigned short)f2bf(v.w);
  ((ushort4*)out)[i] = o;
}

// ---- per-dst edge counts ----
__global__ __launch_bounds__(256) void count_k(const int* __restrict__ dst,
                                               int* __restrict__ cnt, int nE) {
  int i = blockIdx.x * 256 + threadIdx.x;
  if (i < nE) atomicAdd(&cnt[dst[i]], 1);
}

__global__ __launch_bounds__(256) void inv_k(const int* __restrict__ cnt,
                                             float* __restrict__ inv, int n) {
  int i = blockIdx.x * 256 + threadIdx.x;
  if (i < n) { int c = cnt[i]; inv[i] = 1.0f / (float)(c > 1 ? c : 1); }
}

// ---- scan stage 1: per-256-block sums of cnt ----
__device__ __forceinline__ int wave_incl_scan(int v, int lane) {
#pragma unroll
  for (int off = 1; off < 64; off <<= 1) {
    int y = __shfl_up(v, off);
    if (lane >= off) v += y;
  }
  return v;
}

__global__ __launch_bounds__(256) void scan1_k(const int* __restrict__ cnt,
                                               int* __restrict__ bsum, int n) {
  int b = blockIdx.x, tid = threadIdx.x;
  int i = b * 256 + tid;
  int v = (i < n) ? cnt[i] : 0;
  int lane = tid & 63, wid = tid >> 6;
  __shared__ int ws[4];
  int s = wave_incl_scan(v, lane);
  if (lane == 63) ws[wid] = s;
  __syncthreads();
  if (tid == 0) bsum[b] = ws[0] + ws[1] + ws[2] + ws[3];
}

__global__ __launch_bounds__(256) void scan2_k(const int* __restrict__ cnt,
                                               const int* __restrict__ bsum,
                                               int* __restrict__ ofs,
                                               int* __restrict__ cur, int n) {
  int b = blockIdx.x, tid = threadIdx.x;
  int lane = tid & 63, wid = tid >> 6;
  __shared__ int wsA[4], wsB[4];
  int p = 0;
  for (int j = tid; j < b; j += 256) p += bsum[j];
#pragma unroll
  for (int off = 32; off; off >>= 1) p += __shfl_xor(p, off);
  if (lane == 0) wsA[wid] = p;
  __syncthreads();
  int base = wsA[0] + wsA[1] + wsA[2] + wsA[3];
  int i = b * 256 + tid;
  int v = (i < n) ? cnt[i] : 0;
  int s = wave_incl_scan(v, lane);
  if (lane == 63) wsB[wid] = s;
  __syncthreads();
  int woff = 0;
  for (int w = 0; w < wid; w++) woff += wsB[w];
  int excl = base + woff + s - v;
  if (i < n) { ofs[i] = excl; cur[i] = excl; }
}

// ---- bucket fill: counting-sort edges by dst ----
__global__ __launch_bounds__(256) void fill_k(const int* __restrict__ eidx,
                                              int* __restrict__ cur,
                                              int* __restrict__ bucket,
                                              int base, int nE) {
  int i = blockIdx.x * 256 + threadIdx.x;
  if (i >= nE) return;
  int s = eidx[i];
  int d = eidx[nE + i];
  int pos = atomicAdd(&cur[base + d], 1);
  bucket[pos] = s;
}

// ---- CSR gather-mean into bf16 agg (inv folded in); one wave per dst node ----
template <int RELU>
__global__ __launch_bounds__(256)
void agg_bf_k(const ushort_t* __restrict__ xsrc, const int* __restrict__ ofs,
              const int* __restrict__ cnt, const float* __restrict__ inv,
              const int* __restrict__ bucket, ushort_t* __restrict__ agg, int n) {
  int w = (int)(((size_t)blockIdx.x * 256 + threadIdx.x) >> 6);
  int lane = threadIdx.x & 63;
  if (w >= n) return;
  int beg = ofs[w];
  int c = cnt[w];
  float iv = inv[w];
  float ax = 0.f, ay = 0.f;
  int j = 0;
  for (; j + 2 <= c; j += 2) {
    int s0 = bucket[beg + j], s1 = bucket[beg + j + 1];
    uint v0 = *(const uint*)(xsrc + (size_t)s0 * D128 + lane * 2);
    uint v1 = *(const uint*)(xsrc + (size_t)s1 * D128 + lane * 2);
    float x0 = bf_lo(v0), y0 = bf_hi(v0);
    float x1 = bf_lo(v1), y1 = bf_hi(v1);
    if (RELU) {
      x0 = fmaxf(x0, 0.f); y0 = fmaxf(y0, 0.f);
      x1 = fmaxf(x1, 0.f); y1 = fmaxf(y1, 0.f);
    }
    ax += x0 + x1; ay += y0 + y1;
  }
  if (j < c) {
    int s0 = bucket[beg + j];
    uint v0 = *(const uint*)(xsrc + (size_t)s0 * D128 + lane * 2);
    float x0 = bf_lo(v0), y0 = bf_hi(v0);
    if (RELU) { x0 = fmaxf(x0, 0.f); y0 = fmaxf(y0, 0.f); }
    ax += x0; ay += y0;
  }
  *(uint*)(agg + (size_t)w * D128 + lane * 2) = pack2(ax * iv, ay * iv);
}

// ---- fused SAGE transform, LDS-staged weights, persistent grid-stride ----
//  c_e = agg_e @ Wl_e^T + bl_e + [relu]x @ Wr_e^T ; out = sum_e l2norm(c_e)
//  DUAL: two edge types in one pass. CLF: fuse classifier (out = logits f32).
template <int DUAL, int RELU_X, int CLF>
__global__ __launch_bounds__(DUAL ? 512 : 256, 2)
void sage_k(const ushort_t* __restrict__ agg1, const ushort_t* __restrict__ agg3,
            const ushort_t* __restrict__ x,
            const ushort_t* __restrict__ wlA, const ushort_t* __restrict__ wrA,
            const ushort_t* __restrict__ wlB, const ushort_t* __restrict__ wrB,
            const float* __restrict__ biasA, const float* __restrict__ biasB,
            const float* __restrict__ clfW, const float* __restrict__ clfb,
            void* __restrict__ outv, int ntiles) {
  extern __shared__ char smem[];
  const int tid = threadIdx.x;
  const int NT = DUAL ? 512 : 256;
  const int NMAT = DUAL ? 4 : 2;

  // stage weights into LDS with slot^row swizzle (T2): chunk = 16B
  for (int c = tid; c < NMAT * 2048; c += NT) {
    int m = c >> 11, cc = c & 2047;
    int row = cc >> 4, slot = cc & 15;
    const ushort_t* W = (m == 0) ? wlA : (m == 1) ? wrA : (m == 2) ? wlB : wrB;
    uint4 v = *((const uint4*)W + cc);
    *(uint4*)(smem + m * 32768 + row * 256 + ((slot ^ (row & 15)) << 4)) = v;
  }
  __syncthreads();

  int lane = tid & 63;
  int r = lane & 15, kh = lane >> 4;
  int wid = tid >> 6;
  int nw = NT >> 6;

  float bvA[8], bvB[8], w0[8], w1[8];
#pragma unroll
  for (int t = 0; t < 8; t++) {
    bvA[t] = biasA[t * 16 + r];
    if (DUAL) bvB[t] = biasB[t * 16 + r];
    if (CLF) { w0[t] = clfW[t * 16 + r]; w1[t] = clfW[D128 + t * 16 + r]; }
  }
  float cb0 = 0.f, cb1 = 0.f;
  if (CLF) { cb0 = clfb[0]; cb1 = clfb[1]; }

  const int rb = r * 256;

  for (int tile = blockIdx.x * nw + wid; tile < ntiles; tile += gridDim.x * nw) {
    size_t n0 = (size_t)tile * 16;
    size_t rowe = (n0 + r) * D128;

    uint4 A1[4], A3[4], X[4];
#pragma unroll
    for (int kk = 0; kk < 4; kk++) {
      size_t eo = rowe + kk * 32 + kh * 8;
      A1[kk] = *(const uint4*)(agg1 + eo);
      if (DUAL) A3[kk] = *(const uint4*)(agg3 + eo);
      X[kk] = *(const uint4*)(x + eo);
      if (RELU_X) {
        X[kk].x = relu_pk2(X[kk].x); X[kk].y = relu_pk2(X[kk].y);
        X[kk].z = relu_pk2(X[kk].z); X[kk].w = relu_pk2(X[kk].w);
      }
    }

    f32x4 acc1[8], acc3[8];
#pragma unroll
    for (int t = 0; t < 8; t++) {
      acc1[t] = (f32x4){0.f, 0.f, 0.f, 0.f};
      acc3[t] = (f32x4){0.f, 0.f, 0.f, 0.f};
    }

#pragma unroll
    for (int kk = 0; kk < 4; kk++) {
      int so = (((kk << 2) + kh) ^ r) << 4;  // swizzled 16B slot
      bf16x8 af1 = as_h(A1[kk]);
      bf16x8 xf = as_h(X[kk]);
      bf16x8 af3 = as_h(A3[kk]);
#pragma unroll
      for (int t = 0; t < 8; t++) {
        const char* p = smem + t * 4096 + rb + so;
        bf16x8 wla = *(const bf16x8*)(p);
        bf16x8 wra = *(const bf16x8*)(p + 32768);
        acc1[t] = __builtin_amdgcn_mfma_f32_16x16x32_bf16(af1, wla, acc1[t], 0, 0, 0);
        acc1[t] = __builtin_amdgcn_mfma_f32_16x16x32_bf16(xf, wra, acc1[t], 0, 0, 0);
        if (DUAL) {
          bf16x8 wlb = *(const bf16x8*)(p + 65536);
          bf16x8 wrb = *(const bf16x8*)(p + 98304);
          acc3[t] = __builtin_amdgcn_mfma_f32_16x16x32_bf16(af3, wlb, acc3[t], 0, 0, 0);
          acc3[t] = __builtin_amdgcn_mfma_f32_16x16x32_bf16(xf, wrb, acc3[t], 0, 0, 0);
        }
      }
    }

    // epilogue: bias, per-node squared sums, 16-lane reduce, normalize
    float s1[4] = {0.f, 0.f, 0.f, 0.f}, s3[4] = {0.f, 0.f, 0.f, 0.f};
#pragma unroll
    for (int t = 0; t < 8; t++) {
#pragma unroll
      for (int q = 0; q < 4; q++) {
        float c1 = acc1[t][q] + bvA[t];
        acc1[t][q] = c1; s1[q] += c1 * c1;
        if (DUAL) {
          float c3 = acc3[t][q] + bvB[t];
          acc3[t][q] = c3; s3[q] += c3 * c3;
        }
      }
    }
#pragma unroll
    for (int off = 1; off < 16; off <<= 1) {
#pragma unroll
      for (int q = 0; q < 4; q++) {
        s1[q] += __shfl_xor(s1[q], off);
        if (DUAL) s3[q] += __shfl_xor(s3[q], off);
      }
    }
    float rn1[4], rn3[4];
#pragma unroll
    for (int q = 0; q < 4; q++) {
      rn1[q] = 1.0f / fmaxf(sqrtf(s1[q]), 1e-12f);
      rn3[q] = DUAL ? 1.0f / fmaxf(sqrtf(s3[q]), 1e-12f) : 0.f;
    }

    if (CLF) {
      float p0[4] = {0.f, 0.f, 0.f, 0.f}, p1[4] = {0.f, 0.f, 0.f, 0.f};
#pragma unroll
      for (int t = 0; t < 8; t++) {
#pragma unroll
        for (int q = 0; q < 4; q++) {
          float val = acc1[t][q] * rn1[q] + acc3[t][q] * rn3[q];
          p0[q] += val * w0[t];
          p1[q] += val * w1[t];
        }
      }
#pragma unroll
      for (int off = 1; off < 16; off <<= 1) {
#pragma unroll
        for (int q = 0; q < 4; q++) {
          p0[q] += __shfl_xor(p0[q], off);
          p1[q] += __shfl_xor(p1[q], off);
        }
      }
      if (r == 0) {
#pragma unroll
        for (int q = 0; q < 4; q++) {
          size_t node = n0 + kh * 4 + q;
          float2 o; o.x = p0[q] + cb0; o.y = p1[q] + cb1;
          *(float2*)((float*)outv + node * 2) = o;
        }
      }
    } else {
      ushort_t* outb = (ushort_t*)outv;
#pragma unroll
      for (int t = 0; t < 8; t++) {
#pragma unroll
        for (int q = 0; q < 4; q++) {
          float val = acc1[t][q] * rn1[q];
          if (DUAL) val += acc3[t][q] * rn3[q];
          float pv = __shfl_xor(val, 1);
          if ((r & 1) == 0) {
            size_t node = n0 + kh * 4 + q;
            *(uint*)(outb + node * D128 + t * 16 + r) = pack2(val, pv);
          }
        }
      }
    }
  }
}

extern "C" void kernel_launch(void* const* d_in, const int* in_sizes, int n_in,
                              void* d_out, int out_size, void* d_ws, size_t ws_size,
                              hipStream_t stream) {
  const float* emb_app = (const float*)d_in[0];
  const float* emb_mer = (const float*)d_in[1];
  const float* emb_dev = (const float*)d_in[2];
  const float* c1Wl = (const float*)d_in[3];
  const float* c1bl = (const float*)d_in[4];
  const float* c1Wr = (const float*)d_in[5];
  const float* c2Wl = (const float*)d_in[6];
  const float* c2bl = (const float*)d_in[7];
  const float* c2Wr = (const float*)d_in[8];
  const float* clfW = (const float*)d_in[9];
  const float* clfb = (const float*)d_in[10];
  const int* e0 = (const int*)d_in[11];
  const int* e1 = (const int*)d_in[12];
  const int* e2 = (const int*)d_in[13];
  const int* e3 = (const int*)d_in[14];

  const int NA = in_sizes[0] / D128;
  const int NM = in_sizes[1] / D128;
  const int ND = in_sizes[2] / D128;
  const int E = in_sizes[11] / 2;
  float* out = (float*)d_out;

  char* wsb = (char*)d_ws;
  size_t off = 0;
  auto alloc = [&](size_t bytes) -> char* {
    char* p = wsb + off;
    off += (bytes + 511) & ~(size_t)511;
    return p;
  };
  ushort_t* wl1 = (ushort_t*)alloc((size_t)4 * 16384 * 2);
  ushort_t* wr1 = (ushort_t*)alloc((size_t)4 * 16384 * 2);
  ushort_t* wl2 = (ushort_t*)alloc((size_t)4 * 16384 * 2);
  ushort_t* wr2 = (ushort_t*)alloc((size_t)4 * 16384 * 2);
  ushort_t* eapp = (ushort_t*)alloc((size_t)NA * D128 * 2);
  ushort_t* emer = (ushort_t*)alloc((size_t)NM * D128 * 2);
  ushort_t* edev = (ushort_t*)alloc((size_t)ND * D128 * 2);
  ushort_t* h1a = (ushort_t*)alloc((size_t)NA * D128 * 2);
  ushort_t* h1m = (ushort_t*)alloc((size_t)NM * D128 * 2);
  ushort_t* h1d = (ushort_t*)alloc((size_t)ND * D128 * 2);
  ushort_t* aggA = (ushort_t*)alloc((size_t)NA * D128 * 2);
  ushort_t* aggB = (ushort_t*)alloc((size_t)NA * D128 * 2);
  int ncnt = NM + NA + ND + NA;
  int nb = (ncnt + 255) / 256;
  int* cnt = (int*)alloc((size_t)ncnt * 4);
  float* inv = (float*)alloc((size_t)ncnt * 4);
  int* ofs = (int*)alloc((size_t)ncnt * 4);
  int* cur = (int*)alloc((size_t)ncnt * 4);
  int* bsum = (int*)alloc((size_t)nb * 4);
  int* bucket = (int*)alloc((size_t)4 * E * 4);
  (void)ws_size;  // ~300 MB of workspace

  int b0 = 0, b1 = NM, b2 = NM + NA, b3 = NM + NA + ND;

  // allow 128 KiB dynamic LDS for the dual kernels (gfx950 has 160 KiB/CU)
  hipFuncSetAttribute((const void*)sage_k<1, 0, 0>,
                      hipFuncAttributeMaxDynamicSharedMemorySize, 131072);
  hipFuncSetAttribute((const void*)sage_k<1, 1, 1>,
                      hipFuncAttributeMaxDynamicSharedMemorySize, 131072);
  hipFuncSetAttribute((const void*)sage_k<0, 0, 0>,
                      hipFuncAttributeMaxDynamicSharedMemorySize, 65536);

  // ---- conversions to bf16 ----
  cvt4_k<<<64, 256, 0, stream>>>(c1Wl, wl1, 16384);
  cvt4_k<<<64, 256, 0, stream>>>(c1Wr, wr1, 16384);
  cvt4_k<<<64, 256, 0, stream>>>(c2Wl, wl2, 16384);
  cvt4_k<<<64, 256, 0, stream>>>(c2Wr, wr2, 16384);
  int na4 = NA * 32, nm4 = NM * 32, nd4 = ND * 32;
  cvt4_k<<<(na4 + 255) / 256, 256, 0, stream>>>(emb_app, eapp, na4);
  cvt4_k<<<(nm4 + 255) / 256, 256, 0, stream>>>(emb_mer, emer, nm4);
  cvt4_k<<<(nd4 + 255) / 256, 256, 0, stream>>>(emb_dev, edev, nd4);

  // ---- degree counts + CSR build ----
  hipMemsetAsync(cnt, 0, (size_t)ncnt * 4, stream);
  int cgrid = (E + 255) / 256;
  count_k<<<cgrid, 256, 0, stream>>>(e0 + E, cnt + b0, E);
  count_k<<<cgrid, 256, 0, stream>>>(e1 + E, cnt + b1, E);
  count_k<<<cgrid, 256, 0, stream>>>(e2 + E, cnt + b2, E);
  count_k<<<cgrid, 256, 0, stream>>>(e3 + E, cnt + b3, E);
  inv_k<<<(ncnt + 255) / 256, 256, 0, stream>>>(cnt, inv, ncnt);
  scan1_k<<<nb, 256, 0, stream>>>(cnt, bsum, ncnt);
  scan2_k<<<nb, 256, 0, stream>>>(cnt, bsum, ofs, cur, ncnt);
  fill_k<<<cgrid, 256, 0, stream>>>(e0, cur, bucket, b0, E);
  fill_k<<<cgrid, 256, 0, stream>>>(e1, cur, bucket, b1, E);
  fill_k<<<cgrid, 256, 0, stream>>>(e2, cur, bucket, b2, E);
  fill_k<<<cgrid, 256, 0, stream>>>(e3, cur, bucket, b3, E);

  auto wgrid = [](int n) { return (n + 3) / 4; };  // one wave per node
  int tilesA = NA / 16, tilesM = NM / 16, tilesD = ND / 16;

  // ---- layer 1 ----
  // k0: app -> mer
  agg_bf_k<0><<<wgrid(NM), 256, 0, stream>>>(eapp, ofs + b0, cnt + b0, inv + b0, bucket, aggA, NM);
  sage_k<0, 0, 0><<<512, 256, 65536, stream>>>(aggA, nullptr, emer,
      wl1 + 0 * 16384, wr1 + 0 * 16384, nullptr, nullptr,
      c1bl + 0 * D128, nullptr, nullptr, nullptr, h1m, tilesM);
  // k2: app -> dev
  agg_bf_k<0><<<wgrid(ND), 256, 0, stream>>>(eapp, ofs + b2, cnt + b2, inv + b2, bucket, aggA, ND);
  sage_k<0, 0, 0><<<512, 256, 65536, stream>>>(aggA, nullptr, edev,
      wl1 + 2 * 16384, wr1 + 2 * 16384, nullptr, nullptr,
      c1bl + 2 * D128, nullptr, nullptr, nullptr, h1d, tilesD);
  // k1 + k3: mer -> app, dev -> app (dual)
  agg_bf_k<0><<<wgrid(NA), 256, 0, stream>>>(emer, ofs + b1, cnt + b1, inv + b1, bucket, aggA, NA);
  agg_bf_k<0><<<wgrid(NA), 256, 0, stream>>>(edev, ofs + b3, cnt + b3, inv + b3, bucket, aggB, NA);
  sage_k<1, 0, 0><<<256, 512, 131072, stream>>>(aggA, aggB, eapp,
      wl1 + 1 * 16384, wr1 + 1 * 16384, wl1 + 3 * 16384, wr1 + 3 * 16384,
      c1bl + 1 * D128, c1bl + 3 * D128, nullptr, nullptr, h1a, tilesA);

  // ---- layer 2 (dst=app only) + fused classifier ----
  agg_bf_k<1><<<wgrid(NA), 256, 0, stream>>>(h1m, ofs + b1, cnt + b1, inv + b1, bucket, aggA, NA);
  agg_bf_k<1><<<wgrid(NA), 256, 0, stream>>>(h1d, ofs + b3, cnt + b3, inv + b3, bucket, aggB, NA);
  sage_k<1, 1, 1><<<256, 512, 131072, stream>>>(aggA, aggB, h1a,
      wl2 + 1 * 16384, wr2 + 1 * 16384, wl2 + 3 * 16384, wr2 + 3 * 16384,
      c2bl + 1 * D128, c2bl + 3 * D128, clfW, clfb, out, tilesA);
}

// Round 5
// 827.606 us; speedup vs baseline: 1.7649x; 1.7649x over previous
//
#include <hip/hip_runtime.h>
#include <hip/hip_bf16.h>

#define D128 128

typedef __attribute__((ext_vector_type(8))) short bf16x8;
typedef __attribute__((ext_vector_type(4))) float f32x4;
typedef unsigned int uint;
typedef unsigned short ushort_t;

union U4 { uint4 u; bf16x8 h; };
__device__ __forceinline__ bf16x8 as_h(uint4 u) { U4 x; x.u = u; return x.h; }

__device__ __forceinline__ short f2bf(float f) {
  union { float f; unsigned u; } v; v.f = f;
  unsigned r = v.u + 0x7FFFu + ((v.u >> 16) & 1u);  // RNE
  return (short)(r >> 16);
}
__device__ __forceinline__ float bf_lo(uint v) {
  union { uint u; float f; } x; x.u = v << 16; return x.f;
}
__device__ __forceinline__ float bf_hi(uint v) {
  union { uint u; float f; } x; x.u = v & 0xFFFF0000u; return x.f;
}
__device__ __forceinline__ uint pack2(float a, float b) {
  return (uint)(unsigned short)f2bf(a) | ((uint)(unsigned short)f2bf(b) << 16);
}

// ---- f32 -> bf16, 4 elements/thread ----
__global__ __launch_bounds__(256) void cvt4_k(const float* __restrict__ in,
                                              ushort_t* __restrict__ out, int n4) {
  int i = blockIdx.x * 256 + threadIdx.x;
  if (i >= n4) return;
  float4 v = ((const float4*)in)[i];
  ushort4 o;
  o.x = (unsigned short)f2bf(v.x); o.y = (unsigned short)f2bf(v.y);
  o.z = (unsigned short)f2bf(v.z); o.w = (unsigned short)f2bf(v.w);
  ((ushort4*)out)[i] = o;
}

// ---- per-dst edge counts ----
__global__ __launch_bounds__(256) void count_k(const int* __restrict__ dst,
                                               int* __restrict__ cnt, int nE) {
  int i = blockIdx.x * 256 + threadIdx.x;
  if (i < nE) atomicAdd(&cnt[dst[i]], 1);
}

__global__ __launch_bounds__(256) void inv_k(const int* __restrict__ cnt,
                                             float* __restrict__ inv, int n) {
  int i = blockIdx.x * 256 + threadIdx.x;
  if (i < n) { int c = cnt[i]; inv[i] = 1.0f / (float)(c > 1 ? c : 1); }
}

// ---- scan stage 1: per-256-block sums of cnt ----
__device__ __forceinline__ int wave_incl_scan(int v, int lane) {
#pragma unroll
  for (int off = 1; off < 64; off <<= 1) {
    int y = __shfl_up(v, off);
    if (lane >= off) v += y;
  }
  return v;
}

__global__ __launch_bounds__(256) void scan1_k(const int* __restrict__ cnt,
                                               int* __restrict__ bsum, int n) {
  int b = blockIdx.x, tid = threadIdx.x;
  int i = b * 256 + tid;
  int v = (i < n) ? cnt[i] : 0;
  int lane = tid & 63, wid = tid >> 6;
  __shared__ int ws[4];
  int s = wave_incl_scan(v, lane);
  if (lane == 63) ws[wid] = s;
  __syncthreads();
  if (tid == 0) bsum[b] = ws[0] + ws[1] + ws[2] + ws[3];
}

__global__ __launch_bounds__(256) void scan2_k(const int* __restrict__ cnt,
                                               const int* __restrict__ bsum,
                                               int* __restrict__ ofs,
                                               int* __restrict__ cur, int n) {
  int b = blockIdx.x, tid = threadIdx.x;
  int lane = tid & 63, wid = tid >> 6;
  __shared__ int wsA[4], wsB[4];
  int p = 0;
  for (int j = tid; j < b; j += 256) p += bsum[j];
#pragma unroll
  for (int off = 32; off; off >>= 1) p += __shfl_xor(p, off);
  if (lane == 0) wsA[wid] = p;
  __syncthreads();
  int base = wsA[0] + wsA[1] + wsA[2] + wsA[3];
  int i = b * 256 + tid;
  int v = (i < n) ? cnt[i] : 0;
  int s = wave_incl_scan(v, lane);
  if (lane == 63) wsB[wid] = s;
  __syncthreads();
  int woff = 0;
  for (int w = 0; w < wid; w++) woff += wsB[w];
  int excl = base + woff + s - v;
  if (i < n) { ofs[i] = excl; cur[i] = excl; }
}

// ---- bucket fill: counting-sort edges by dst ----
__global__ __launch_bounds__(256) void fill_k(const int* __restrict__ eidx,
                                              int* __restrict__ cur,
                                              int* __restrict__ bucket,
                                              int base, int nE) {
  int i = blockIdx.x * 256 + threadIdx.x;
  if (i >= nE) return;
  int s = eidx[i];
  int d = eidx[nE + i];
  int pos = atomicAdd(&cur[base + d], 1);
  bucket[pos] = s;
}

// ---- CSR gather-mean into bf16 agg (inv folded in); one wave per dst node ----
template <int RELU>
__global__ __launch_bounds__(256)
void agg_bf_k(const ushort_t* __restrict__ xsrc, const int* __restrict__ ofs,
              const int* __restrict__ cnt, const float* __restrict__ inv,
              const int* __restrict__ bucket, ushort_t* __restrict__ agg, int n) {
  int w = (int)(((size_t)blockIdx.x * 256 + threadIdx.x) >> 6);
  int lane = threadIdx.x & 63;
  if (w >= n) return;
  int beg = ofs[w];
  int c = cnt[w];
  float iv = inv[w];
  float ax = 0.f, ay = 0.f;
  int j = 0;
  for (; j + 2 <= c; j += 2) {
    int s0 = bucket[beg + j], s1 = bucket[beg + j + 1];
    uint v0 = *(const uint*)(xsrc + (size_t)s0 * D128 + lane * 2);
    uint v1 = *(const uint*)(xsrc + (size_t)s1 * D128 + lane * 2);
    float x0 = bf_lo(v0), y0 = bf_hi(v0);
    float x1 = bf_lo(v1), y1 = bf_hi(v1);
    if (RELU) {
      x0 = fmaxf(x0, 0.f); y0 = fmaxf(y0, 0.f);
      x1 = fmaxf(x1, 0.f); y1 = fmaxf(y1, 0.f);
    }
    ax += x0 + x1; ay += y0 + y1;
  }
  if (j < c) {
    int s0 = bucket[beg + j];
    uint v0 = *(const uint*)(xsrc + (size_t)s0 * D128 + lane * 2);
    float x0 = bf_lo(v0), y0 = bf_hi(v0);
    if (RELU) { x0 = fmaxf(x0, 0.f); y0 = fmaxf(y0, 0.f); }
    ax += x0; ay += y0;
  }
  *(uint*)(agg + (size_t)w * D128 + lane * 2) = pack2(ax * iv, ay * iv);
}

// ---- fused SAGE transform (single edge type), LDS-staged weights ----
//  c = agg @ Wl^T + bl + x @ Wr^T ; v = l2norm(c)
//  XBF:  x buffer is bf16 (else f32, converted in-kernel)
//  ACC:  v += prevf (f32 partial) before RELU/CLF
//  BFOUT: store v bf16 (R3-proven pack2 store); else f32 scalar store (R2)
//  OUTRELU: relu before store
//  CLF:  classifier from registers -> logits f32 (no store of v)
template <int XBF, int ACC, int BFOUT, int OUTRELU, int CLF>
__global__ __launch_bounds__(512)
void sage5(const ushort_t* __restrict__ agg, const void* __restrict__ xv,
           const ushort_t* __restrict__ wl, const ushort_t* __restrict__ wr,
           const float* __restrict__ bias, const float* __restrict__ prevf,
           const float* __restrict__ clfW, const float* __restrict__ clfb,
           void* __restrict__ outv, int ntiles) {
  extern __shared__ char smem[];  // 65536 = 2 x (128x128 bf16) swizzled
  const int tid = threadIdx.x;

  for (int c = tid; c < 4096; c += 512) {
    int m = c >> 11, cc = c & 2047;
    int row = cc >> 4, slot = cc & 15;
    const ushort_t* W = m ? wr : wl;
    uint4 v = *((const uint4*)W + cc);
    *(uint4*)(smem + m * 32768 + row * 256 + ((slot ^ (row & 15)) << 4)) = v;
  }
  __syncthreads();

  int wid = tid >> 6, lane = tid & 63;
  int r = lane & 15, kh = lane >> 4;
  int tile = blockIdx.x * 8 + wid;
  if (tile >= ntiles) return;
  size_t n0 = (size_t)tile * 16;

  // fragments
  const ushort_t* ap = agg + (n0 + r) * D128 + kh * 8;
  uint4 A[4];
  bf16x8 XF[4];
#pragma unroll
  for (int kk = 0; kk < 4; kk++) A[kk] = *(const uint4*)(ap + kk * 32);
  if (XBF) {
    const ushort_t* xp = (const ushort_t*)xv + (n0 + r) * D128 + kh * 8;
#pragma unroll
    for (int kk = 0; kk < 4; kk++) XF[kk] = as_h(*(const uint4*)(xp + kk * 32));
  } else {
    const float* xp = (const float*)xv + (n0 + r) * D128 + kh * 8;
#pragma unroll
    for (int kk = 0; kk < 4; kk++) {
      f32x4 x0 = *(const f32x4*)(xp + kk * 32);
      f32x4 x1 = *(const f32x4*)(xp + kk * 32 + 4);
#pragma unroll
      for (int j = 0; j < 4; j++) {
        XF[kk][j] = f2bf(x0[j]);
        XF[kk][j + 4] = f2bf(x1[j]);
      }
    }
  }

  f32x4 acc[8];
#pragma unroll
  for (int t = 0; t < 8; t++) acc[t] = (f32x4){0.f, 0.f, 0.f, 0.f};

#pragma unroll
  for (int kk = 0; kk < 4; kk++) {
    int so = (((kk << 2) + kh) ^ r) << 4;  // swizzled 16B slot
    bf16x8 af = as_h(A[kk]);
    bf16x8 xf = XF[kk];
#pragma unroll
    for (int t = 0; t < 8; t++) {
      const char* p = smem + t * 4096 + r * 256 + so;
      bf16x8 bwl = *(const bf16x8*)(p);
      bf16x8 bwr = *(const bf16x8*)(p + 32768);
      acc[t] = __builtin_amdgcn_mfma_f32_16x16x32_bf16(af, bwl, acc[t], 0, 0, 0);
      acc[t] = __builtin_amdgcn_mfma_f32_16x16x32_bf16(xf, bwr, acc[t], 0, 0, 0);
    }
  }

  // bias + per-node squared sums + 16-lane reduce -> 1/||c||
  float s[4] = {0.f, 0.f, 0.f, 0.f};
#pragma unroll
  for (int t = 0; t < 8; t++) {
    float bv = bias[t * 16 + r];
#pragma unroll
    for (int q = 0; q < 4; q++) {
      float c = acc[t][q] + bv;
      acc[t][q] = c;
      s[q] += c * c;
    }
  }
#pragma unroll
  for (int off = 1; off < 16; off <<= 1) {
#pragma unroll
    for (int q = 0; q < 4; q++) s[q] += __shfl_xor(s[q], off);
  }
  float rn[4];
#pragma unroll
  for (int q = 0; q < 4; q++) rn[q] = 1.0f / fmaxf(sqrtf(s[q]), 1e-12f);

  if (CLF) {
    // classifier from registers (R3-proven) + f32 prev partial
    float w0[8], w1[8];
#pragma unroll
    for (int t = 0; t < 8; t++) {
      w0[t] = clfW[t * 16 + r];
      w1[t] = clfW[D128 + t * 16 + r];
    }
    float p0[4] = {0.f, 0.f, 0.f, 0.f}, p1[4] = {0.f, 0.f, 0.f, 0.f};
#pragma unroll
    for (int t = 0; t < 8; t++) {
#pragma unroll
      for (int q = 0; q < 4; q++) {
        float val = acc[t][q] * rn[q];
        if (ACC) {
          size_t node = n0 + kh * 4 + q;
          val += prevf[node * D128 + t * 16 + r];
        }
        p0[q] += val * w0[t];
        p1[q] += val * w1[t];
      }
    }
#pragma unroll
    for (int off = 1; off < 16; off <<= 1) {
#pragma unroll
      for (int q = 0; q < 4; q++) {
        p0[q] += __shfl_xor(p0[q], off);
        p1[q] += __shfl_xor(p1[q], off);
      }
    }
    if (r == 0) {
      float cb0 = clfb[0], cb1 = clfb[1];
#pragma unroll
      for (int q = 0; q < 4; q++) {
        size_t node = n0 + kh * 4 + q;
        float2 o; o.x = p0[q] + cb0; o.y = p1[q] + cb1;
        *(float2*)((float*)outv + node * 2) = o;
      }
    }
  } else {
#pragma unroll
    for (int t = 0; t < 8; t++) {
#pragma unroll
      for (int q = 0; q < 4; q++) {
        float val = acc[t][q] * rn[q];
        size_t node = n0 + kh * 4 + q;
        if (ACC) val += prevf[node * D128 + t * 16 + r];
        if (OUTRELU) val = fmaxf(val, 0.f);
        if (BFOUT) {
          float pv = __shfl_xor(val, 1);
          if ((r & 1) == 0)
            *(uint*)((ushort_t*)outv + node * D128 + t * 16 + r) = pack2(val, pv);
        } else {
          ((float*)outv)[node * D128 + t * 16 + r] = val;
        }
      }
    }
  }
}

extern "C" void kernel_launch(void* const* d_in, const int* in_sizes, int n_in,
                              void* d_out, int out_size, void* d_ws, size_t ws_size,
                              hipStream_t stream) {
  const float* emb_app = (const float*)d_in[0];
  const float* emb_mer = (const float*)d_in[1];
  const float* emb_dev = (const float*)d_in[2];
  const float* c1Wl = (const float*)d_in[3];
  const float* c1bl = (const float*)d_in[4];
  const float* c1Wr = (const float*)d_in[5];
  const float* c2Wl = (const float*)d_in[6];
  const float* c2bl = (const float*)d_in[7];
  const float* c2Wr = (const float*)d_in[8];
  const float* clfW = (const float*)d_in[9];
  const float* clfb = (const float*)d_in[10];
  const int* e0 = (const int*)d_in[11];
  const int* e1 = (const int*)d_in[12];
  const int* e2 = (const int*)d_in[13];
  const int* e3 = (const int*)d_in[14];

  const int NA = in_sizes[0] / D128;
  const int NM = in_sizes[1] / D128;
  const int ND = in_sizes[2] / D128;
  const int E = in_sizes[11] / 2;
  float* out = (float*)d_out;

  char* wsb = (char*)d_ws;
  size_t off = 0;
  auto alloc = [&](size_t bytes) -> char* {
    char* p = wsb + off;
    off += (bytes + 511) & ~(size_t)511;
    return p;
  };
  ushort_t* wl1 = (ushort_t*)alloc((size_t)4 * 16384 * 2);
  ushort_t* wr1 = (ushort_t*)alloc((size_t)4 * 16384 * 2);
  ushort_t* wl2 = (ushort_t*)alloc((size_t)4 * 16384 * 2);
  ushort_t* wr2 = (ushort_t*)alloc((size_t)4 * 16384 * 2);
  ushort_t* eapp = (ushort_t*)alloc((size_t)NA * D128 * 2);
  ushort_t* emer = (ushort_t*)alloc((size_t)NM * D128 * 2);
  ushort_t* edev = (ushort_t*)alloc((size_t)ND * D128 * 2);
  ushort_t* h1m = (ushort_t*)alloc((size_t)NM * D128 * 2);  // bf16 raw
  ushort_t* h1d = (ushort_t*)alloc((size_t)ND * D128 * 2);  // bf16 raw
  float* h1a = (float*)alloc((size_t)NA * D128 * 4);        // f32, relu'd
  float* h2a = (float*)alloc((size_t)NA * D128 * 4);        // f32 partial
  ushort_t* agg = (ushort_t*)alloc((size_t)NA * D128 * 2);  // bf16, reused
  int ncnt = NM + NA + ND + NA;
  int nb = (ncnt + 255) / 256;
  int* cnt = (int*)alloc((size_t)ncnt * 4);
  float* inv = (float*)alloc((size_t)ncnt * 4);
  int* ofs = (int*)alloc((size_t)ncnt * 4);
  int* cur = (int*)alloc((size_t)ncnt * 4);
  int* bsum = (int*)alloc((size_t)nb * 4);
  int* bucket = (int*)alloc((size_t)4 * E * 4);
  (void)ws_size;  // ~395 MB

  int b0 = 0, b1 = NM, b2 = NM + NA, b3 = NM + NA + ND;

  const int SMEM = 65536;
  hipFuncSetAttribute((const void*)sage5<1, 0, 1, 0, 0>,
                      hipFuncAttributeMaxDynamicSharedMemorySize, SMEM);
  hipFuncSetAttribute((const void*)sage5<1, 0, 0, 0, 0>,
                      hipFuncAttributeMaxDynamicSharedMemorySize, SMEM);
  hipFuncSetAttribute((const void*)sage5<1, 1, 0, 1, 0>,
                      hipFuncAttributeMaxDynamicSharedMemorySize, SMEM);
  hipFuncSetAttribute((const void*)sage5<0, 0, 0, 0, 0>,
                      hipFuncAttributeMaxDynamicSharedMemorySize, SMEM);
  hipFuncSetAttribute((const void*)sage5<0, 1, 0, 0, 1>,
                      hipFuncAttributeMaxDynamicSharedMemorySize, SMEM);

  // ---- conversions to bf16 ----
  cvt4_k<<<64, 256, 0, stream>>>(c1Wl, wl1, 16384);
  cvt4_k<<<64, 256, 0, stream>>>(c1Wr, wr1, 16384);
  cvt4_k<<<64, 256, 0, stream>>>(c2Wl, wl2, 16384);
  cvt4_k<<<64, 256, 0, stream>>>(c2Wr, wr2, 16384);
  int na4 = NA * 32, nm4 = NM * 32, nd4 = ND * 32;
  cvt4_k<<<(na4 + 255) / 256, 256, 0, stream>>>(emb_app, eapp, na4);
  cvt4_k<<<(nm4 + 255) / 256, 256, 0, stream>>>(emb_mer, emer, nm4);
  cvt4_k<<<(nd4 + 255) / 256, 256, 0, stream>>>(emb_dev, edev, nd4);

  // ---- degree counts + CSR build ----
  hipMemsetAsync(cnt, 0, (size_t)ncnt * 4, stream);
  int cgrid = (E + 255) / 256;
  count_k<<<cgrid, 256, 0, stream>>>(e0 + E, cnt + b0, E);
  count_k<<<cgrid, 256, 0, stream>>>(e1 + E, cnt + b1, E);
  count_k<<<cgrid, 256, 0, stream>>>(e2 + E, cnt + b2, E);
  count_k<<<cgrid, 256, 0, stream>>>(e3 + E, cnt + b3, E);
  inv_k<<<(ncnt + 255) / 256, 256, 0, stream>>>(cnt, inv, ncnt);
  scan1_k<<<nb, 256, 0, stream>>>(cnt, bsum, ncnt);
  scan2_k<<<nb, 256, 0, stream>>>(cnt, bsum, ofs, cur, ncnt);
  fill_k<<<cgrid, 256, 0, stream>>>(e0, cur, bucket, b0, E);
  fill_k<<<cgrid, 256, 0, stream>>>(e1, cur, bucket, b1, E);
  fill_k<<<cgrid, 256, 0, stream>>>(e2, cur, bucket, b2, E);
  fill_k<<<cgrid, 256, 0, stream>>>(e3, cur, bucket, b3, E);

  auto wgrid = [](int n) { return (n + 3) / 4; };    // gather: one wave/node
  auto g8 = [](int nt) { return (nt + 7) / 8; };     // sage: 8 waves/block
  int tA = NA / 16, tM = NM / 16, tD = ND / 16;

  // ---- layer 1 ----
  // k0: app -> mer (h1m bf16 raw)
  agg_bf_k<0><<<wgrid(NM), 256, 0, stream>>>(eapp, ofs + b0, cnt + b0, inv + b0, bucket, agg, NM);
  sage5<1, 0, 1, 0, 0><<<g8(tM), 512, SMEM, stream>>>(agg, emer,
      wl1 + 0 * 16384, wr1 + 0 * 16384, c1bl + 0 * D128, nullptr, nullptr, nullptr, h1m, tM);
  // k2: app -> dev (h1d bf16 raw)
  agg_bf_k<0><<<wgrid(ND), 256, 0, stream>>>(eapp, ofs + b2, cnt + b2, inv + b2, bucket, agg, ND);
  sage5<1, 0, 1, 0, 0><<<g8(tD), 512, SMEM, stream>>>(agg, edev,
      wl1 + 2 * 16384, wr1 + 2 * 16384, c1bl + 2 * D128, nullptr, nullptr, nullptr, h1d, tD);
  // k1: mer -> app (f32 raw partial)
  agg_bf_k<0><<<wgrid(NA), 256, 0, stream>>>(emer, ofs + b1, cnt + b1, inv + b1, bucket, agg, NA);
  sage5<1, 0, 0, 0, 0><<<g8(tA), 512, SMEM, stream>>>(agg, eapp,
      wl1 + 1 * 16384, wr1 + 1 * 16384, c1bl + 1 * D128, nullptr, nullptr, nullptr, h1a, tA);
  // k3: dev -> app (add partial, relu, finalize h1a f32)
  agg_bf_k<0><<<wgrid(NA), 256, 0, stream>>>(edev, ofs + b3, cnt + b3, inv + b3, bucket, agg, NA);
  sage5<1, 1, 0, 1, 0><<<g8(tA), 512, SMEM, stream>>>(agg, eapp,
      wl1 + 3 * 16384, wr1 + 3 * 16384, c1bl + 3 * D128, h1a, nullptr, nullptr, h1a, tA);

  // ---- layer 2 (dst=app only) ----
  // k1: mer -> app; gather relu(h1m) -> f32 raw partial h2a
  agg_bf_k<1><<<wgrid(NA), 256, 0, stream>>>(h1m, ofs + b1, cnt + b1, inv + b1, bucket, agg, NA);
  sage5<0, 0, 0, 0, 0><<<g8(tA), 512, SMEM, stream>>>(agg, h1a,
      wl2 + 1 * 16384, wr2 + 1 * 16384, c2bl + 1 * D128, nullptr, nullptr, nullptr, h2a, tA);
  // k3: dev -> app; gather relu(h1d); add h2a; fused classifier
  agg_bf_k<1><<<wgrid(NA), 256, 0, stream>>>(h1d, ofs + b3, cnt + b3, inv + b3, bucket, agg, NA);
  sage5<0, 1, 0, 0, 1><<<g8(tA), 512, SMEM, stream>>>(agg, h1a,
      wl2 + 3 * 16384, wr2 + 3 * 16384, c2bl + 3 * D128, h2a, clfW, clfb, out, tA);
}

// Round 7
// 807.184 us; speedup vs baseline: 1.8095x; 1.0253x over previous
//
#include <hip/hip_runtime.h>
#include <hip/hip_bf16.h>

#define D128 128

typedef __attribute__((ext_vector_type(8))) short bf16x8;
typedef __attribute__((ext_vector_type(4))) float f32x4;
typedef unsigned int uint;
typedef unsigned short ushort_t;

union U4 { uint4 u; bf16x8 h; };
__device__ __forceinline__ bf16x8 as_h(uint4 u) { U4 x; x.u = u; return x.h; }

__device__ __forceinline__ short f2bf(float f) {
  union { float f; unsigned u; } v; v.f = f;
  unsigned r = v.u + 0x7FFFu + ((v.u >> 16) & 1u);  // RNE
  return (short)(r >> 16);
}
__device__ __forceinline__ float bf_lo(uint v) {
  union { uint u; float f; } x; x.u = v << 16; return x.f;
}
__device__ __forceinline__ float bf_hi(uint v) {
  union { uint u; float f; } x; x.u = v & 0xFFFF0000u; return x.f;
}
__device__ __forceinline__ uint pack2(float a, float b) {
  return (uint)(unsigned short)f2bf(a) | ((uint)(unsigned short)f2bf(b) << 16);
}

// ---- fused f32->bf16 conversion: 3 embeddings in one launch ----
__global__ __launch_bounds__(256)
void cvtE_k(const float* __restrict__ ia, const float* __restrict__ im,
            const float* __restrict__ id, ushort_t* __restrict__ oa,
            ushort_t* __restrict__ om, ushort_t* __restrict__ od,
            int na4, int nm4, int nd4) {
  int i = blockIdx.x * 256 + threadIdx.x;
  const float* in; ushort_t* out; int k;
  if (i < na4) { in = ia; out = oa; k = i; }
  else if (i < na4 + nm4) { in = im; out = om; k = i - na4; }
  else if (i < na4 + nm4 + nd4) { in = id; out = od; k = i - na4 - nm4; }
  else return;
  float4 v = ((const float4*)in)[k];
  ushort4 o;
  o.x = (unsigned short)f2bf(v.x); o.y = (unsigned short)f2bf(v.y);
  o.z = (unsigned short)f2bf(v.z); o.w = (unsigned short)f2bf(v.w);
  ((ushort4*)out)[k] = o;
}

// ---- 4 weight tensors in one launch (65536 f32 each = 16384 float4) ----
__global__ __launch_bounds__(256)
void cvtW_k(const float* __restrict__ w0, const float* __restrict__ w1,
            const float* __restrict__ w2, const float* __restrict__ w3,
            ushort_t* __restrict__ o0, ushort_t* __restrict__ o1,
            ushort_t* __restrict__ o2, ushort_t* __restrict__ o3) {
  int y = blockIdx.y;
  const float* in = y == 0 ? w0 : y == 1 ? w1 : y == 2 ? w2 : w3;
  ushort_t* out = y == 0 ? o0 : y == 1 ? o1 : y == 2 ? o2 : o3;
  int i = blockIdx.x * 256 + threadIdx.x;
  if (i >= 16384) return;  // R6 bug: was 4096 -> only 1/4 of each tensor converted
  float4 v = ((const float4*)in)[i];
  ushort4 o;
  o.x = (unsigned short)f2bf(v.x); o.y = (unsigned short)f2bf(v.y);
  o.z = (unsigned short)f2bf(v.z); o.w = (unsigned short)f2bf(v.w);
  ((ushort4*)out)[i] = o;
}

// ---- per-dst edge counts, 4 edge types via blockIdx.y ----
__global__ __launch_bounds__(256)
void count4_k(const int* __restrict__ d0, const int* __restrict__ d1,
              const int* __restrict__ d2, const int* __restrict__ d3,
              int* __restrict__ cnt, int nE, int b0, int b1, int b2, int b3) {
  int i = blockIdx.x * 256 + threadIdx.x;
  if (i >= nE) return;
  int y = blockIdx.y;
  const int* d = y == 0 ? d0 : y == 1 ? d1 : y == 2 ? d2 : d3;
  int base = y == 0 ? b0 : y == 1 ? b1 : y == 2 ? b2 : b3;
  atomicAdd(&cnt[base + d[i]], 1);
}

// ---- scan stage 1 ----
__device__ __forceinline__ int wave_incl_scan(int v, int lane) {
#pragma unroll
  for (int off = 1; off < 64; off <<= 1) {
    int y = __shfl_up(v, off);
    if (lane >= off) v += y;
  }
  return v;
}

__global__ __launch_bounds__(256) void scan1_k(const int* __restrict__ cnt,
                                               int* __restrict__ bsum, int n) {
  int b = blockIdx.x, tid = threadIdx.x;
  int i = b * 256 + tid;
  int v = (i < n) ? cnt[i] : 0;
  int lane = tid & 63, wid = tid >> 6;
  __shared__ int ws[4];
  int s = wave_incl_scan(v, lane);
  if (lane == 63) ws[wid] = s;
  __syncthreads();
  if (tid == 0) bsum[b] = ws[0] + ws[1] + ws[2] + ws[3];
}

// ---- scan stage 2 (+ inv fold) ----
__global__ __launch_bounds__(256) void scan2_k(const int* __restrict__ cnt,
                                               const int* __restrict__ bsum,
                                               int* __restrict__ ofs,
                                               int* __restrict__ cur,
                                               float* __restrict__ inv, int n) {
  int b = blockIdx.x, tid = threadIdx.x;
  int lane = tid & 63, wid = tid >> 6;
  __shared__ int wsA[4], wsB[4];
  int p = 0;
  for (int j = tid; j < b; j += 256) p += bsum[j];
#pragma unroll
  for (int off = 32; off; off >>= 1) p += __shfl_xor(p, off);
  if (lane == 0) wsA[wid] = p;
  __syncthreads();
  int base = wsA[0] + wsA[1] + wsA[2] + wsA[3];
  int i = b * 256 + tid;
  int v = (i < n) ? cnt[i] : 0;
  int s = wave_incl_scan(v, lane);
  if (lane == 63) wsB[wid] = s;
  __syncthreads();
  int woff = 0;
  for (int w = 0; w < wid; w++) woff += wsB[w];
  int excl = base + woff + s - v;
  if (i < n) {
    ofs[i] = excl; cur[i] = excl;
    inv[i] = 1.0f / (float)(v > 1 ? v : 1);
  }
}

// ---- bucket fill, 4 edge types via blockIdx.y ----
__global__ __launch_bounds__(256)
void fill4_k(const int* __restrict__ e0, const int* __restrict__ e1,
             const int* __restrict__ e2, const int* __restrict__ e3,
             int* __restrict__ cur, int* __restrict__ bucket,
             int nE, int b0, int b1, int b2, int b3) {
  int i = blockIdx.x * 256 + threadIdx.x;
  if (i >= nE) return;
  int y = blockIdx.y;
  const int* e = y == 0 ? e0 : y == 1 ? e1 : y == 2 ? e2 : e3;
  int base = y == 0 ? b0 : y == 1 ? b1 : y == 2 ? b2 : b3;
  int s = e[i];
  int d = e[nE + i];
  int pos = atomicAdd(&cur[base + d], 1);
  bucket[pos] = s;
}

// ---- CSR gather-mean, 4-way edge-parallel: one wave per dst node ----
//  4 x 16-lane groups each take every-4th edge (uint4 = 16B per lane),
//  then butterfly-combine; inv folded; bf16 output row (256B coalesced).
template <int RELU>
__global__ __launch_bounds__(256)
void agg_g4(const ushort_t* __restrict__ xsrc, const int* __restrict__ ofs,
            const int* __restrict__ cnt, const float* __restrict__ inv,
            const int* __restrict__ bucket, ushort_t* __restrict__ agg, int n) {
  int w = (int)(((size_t)blockIdx.x * 256 + threadIdx.x) >> 6);
  int lane = threadIdx.x & 63;
  if (w >= n) return;
  int g = lane >> 4, sl = lane & 15;
  int beg = ofs[w], c = cnt[w];
  float iv = inv[w];
  float a[8] = {0.f, 0.f, 0.f, 0.f, 0.f, 0.f, 0.f, 0.f};

  auto accum = [&](uint4 v) {
    float x0 = bf_lo(v.x), x1 = bf_hi(v.x), x2 = bf_lo(v.y), x3 = bf_hi(v.y);
    float x4 = bf_lo(v.z), x5 = bf_hi(v.z), x6 = bf_lo(v.w), x7 = bf_hi(v.w);
    if (RELU) {
      x0 = fmaxf(x0, 0.f); x1 = fmaxf(x1, 0.f); x2 = fmaxf(x2, 0.f); x3 = fmaxf(x3, 0.f);
      x4 = fmaxf(x4, 0.f); x5 = fmaxf(x5, 0.f); x6 = fmaxf(x6, 0.f); x7 = fmaxf(x7, 0.f);
    }
    a[0] += x0; a[1] += x1; a[2] += x2; a[3] += x3;
    a[4] += x4; a[5] += x5; a[6] += x6; a[7] += x7;
  };

  int j = g;
  for (; j + 4 < c; j += 8) {  // unroll 2: two loads in flight per group
    int s0 = bucket[beg + j];
    int s1 = bucket[beg + j + 4];
    uint4 v0 = *(const uint4*)(xsrc + (size_t)s0 * D128 + sl * 8);
    uint4 v1 = *(const uint4*)(xsrc + (size_t)s1 * D128 + sl * 8);
    accum(v0); accum(v1);
  }
  if (j < c) {
    int s0 = bucket[beg + j];
    uint4 v0 = *(const uint4*)(xsrc + (size_t)s0 * D128 + sl * 8);
    accum(v0);
  }

#pragma unroll
  for (int k = 0; k < 8; k++) {
    a[k] += __shfl_xor(a[k], 16);
    a[k] += __shfl_xor(a[k], 32);
  }
  if (g == 0) {
    uint4 o;
    o.x = pack2(a[0] * iv, a[1] * iv);
    o.y = pack2(a[2] * iv, a[3] * iv);
    o.z = pack2(a[4] * iv, a[5] * iv);
    o.w = pack2(a[6] * iv, a[7] * iv);
    *(uint4*)(agg + (size_t)w * D128 + sl * 8) = o;
  }
}

// ---- fused SAGE transform (single edge type), LDS-staged weights ----
//  (unchanged from R5 -- proven)
template <int XBF, int ACC, int BFOUT, int OUTRELU, int CLF>
__global__ __launch_bounds__(512)
void sage5(const ushort_t* __restrict__ agg, const void* __restrict__ xv,
           const ushort_t* __restrict__ wl, const ushort_t* __restrict__ wr,
           const float* __restrict__ bias, const float* __restrict__ prevf,
           const float* __restrict__ clfW, const float* __restrict__ clfb,
           void* __restrict__ outv, int ntiles) {
  extern __shared__ char smem[];  // 65536 = 2 x (128x128 bf16) swizzled
  const int tid = threadIdx.x;

  for (int c = tid; c < 4096; c += 512) {
    int m = c >> 11, cc = c & 2047;
    int row = cc >> 4, slot = cc & 15;
    const ushort_t* W = m ? wr : wl;
    uint4 v = *((const uint4*)W + cc);
    *(uint4*)(smem + m * 32768 + row * 256 + ((slot ^ (row & 15)) << 4)) = v;
  }
  __syncthreads();

  int wid = tid >> 6, lane = tid & 63;
  int r = lane & 15, kh = lane >> 4;
  int tile = blockIdx.x * 8 + wid;
  if (tile >= ntiles) return;
  size_t n0 = (size_t)tile * 16;

  const ushort_t* ap = agg + (n0 + r) * D128 + kh * 8;
  uint4 A[4];
  bf16x8 XF[4];
#pragma unroll
  for (int kk = 0; kk < 4; kk++) A[kk] = *(const uint4*)(ap + kk * 32);
  if (XBF) {
    const ushort_t* xp = (const ushort_t*)xv + (n0 + r) * D128 + kh * 8;
#pragma unroll
    for (int kk = 0; kk < 4; kk++) XF[kk] = as_h(*(const uint4*)(xp + kk * 32));
  } else {
    const float* xp = (const float*)xv + (n0 + r) * D128 + kh * 8;
#pragma unroll
    for (int kk = 0; kk < 4; kk++) {
      f32x4 x0 = *(const f32x4*)(xp + kk * 32);
      f32x4 x1 = *(const f32x4*)(xp + kk * 32 + 4);
#pragma unroll
      for (int j = 0; j < 4; j++) {
        XF[kk][j] = f2bf(x0[j]);
        XF[kk][j + 4] = f2bf(x1[j]);
      }
    }
  }

  f32x4 acc[8];
#pragma unroll
  for (int t = 0; t < 8; t++) acc[t] = (f32x4){0.f, 0.f, 0.f, 0.f};

#pragma unroll
  for (int kk = 0; kk < 4; kk++) {
    int so = (((kk << 2) + kh) ^ r) << 4;
    bf16x8 af = as_h(A[kk]);
    bf16x8 xf = XF[kk];
#pragma unroll
    for (int t = 0; t < 8; t++) {
      const char* p = smem + t * 4096 + r * 256 + so;
      bf16x8 bwl = *(const bf16x8*)(p);
      bf16x8 bwr = *(const bf16x8*)(p + 32768);
      acc[t] = __builtin_amdgcn_mfma_f32_16x16x32_bf16(af, bwl, acc[t], 0, 0, 0);
      acc[t] = __builtin_amdgcn_mfma_f32_16x16x32_bf16(xf, bwr, acc[t], 0, 0, 0);
    }
  }

  float s[4] = {0.f, 0.f, 0.f, 0.f};
#pragma unroll
  for (int t = 0; t < 8; t++) {
    float bv = bias[t * 16 + r];
#pragma unroll
    for (int q = 0; q < 4; q++) {
      float c = acc[t][q] + bv;
      acc[t][q] = c;
      s[q] += c * c;
    }
  }
#pragma unroll
  for (int off = 1; off < 16; off <<= 1) {
#pragma unroll
    for (int q = 0; q < 4; q++) s[q] += __shfl_xor(s[q], off);
  }
  float rn[4];
#pragma unroll
  for (int q = 0; q < 4; q++) rn[q] = 1.0f / fmaxf(sqrtf(s[q]), 1e-12f);

  if (CLF) {
    float w0[8], w1[8];
#pragma unroll
    for (int t = 0; t < 8; t++) {
      w0[t] = clfW[t * 16 + r];
      w1[t] = clfW[D128 + t * 16 + r];
    }
    float p0[4] = {0.f, 0.f, 0.f, 0.f}, p1[4] = {0.f, 0.f, 0.f, 0.f};
#pragma unroll
    for (int t = 0; t < 8; t++) {
#pragma unroll
      for (int q = 0; q < 4; q++) {
        float val = acc[t][q] * rn[q];
        if (ACC) {
          size_t node = n0 + kh * 4 + q;
          val += prevf[node * D128 + t * 16 + r];
        }
        p0[q] += val * w0[t];
        p1[q] += val * w1[t];
      }
    }
#pragma unroll
    for (int off = 1; off < 16; off <<= 1) {
#pragma unroll
      for (int q = 0; q < 4; q++) {
        p0[q] += __shfl_xor(p0[q], off);
        p1[q] += __shfl_xor(p1[q], off);
      }
    }
    if (r == 0) {
      float cb0 = clfb[0], cb1 = clfb[1];
#pragma unroll
      for (int q = 0; q < 4; q++) {
        size_t node = n0 + kh * 4 + q;
        float2 o; o.x = p0[q] + cb0; o.y = p1[q] + cb1;
        *(float2*)((float*)outv + node * 2) = o;
      }
    }
  } else {
#pragma unroll
    for (int t = 0; t < 8; t++) {
#pragma unroll
      for (int q = 0; q < 4; q++) {
        float val = acc[t][q] * rn[q];
        size_t node = n0 + kh * 4 + q;
        if (ACC) val += prevf[node * D128 + t * 16 + r];
        if (OUTRELU) val = fmaxf(val, 0.f);
        if (BFOUT) {
          float pv = __shfl_xor(val, 1);
          if ((r & 1) == 0)
            *(uint*)((ushort_t*)outv + node * D128 + t * 16 + r) = pack2(val, pv);
        } else {
          ((float*)outv)[node * D128 + t * 16 + r] = val;
        }
      }
    }
  }
}

extern "C" void kernel_launch(void* const* d_in, const int* in_sizes, int n_in,
                              void* d_out, int out_size, void* d_ws, size_t ws_size,
                              hipStream_t stream) {
  const float* emb_app = (const float*)d_in[0];
  const float* emb_mer = (const float*)d_in[1];
  const float* emb_dev = (const float*)d_in[2];
  const float* c1Wl = (const float*)d_in[3];
  const float* c1bl = (const float*)d_in[4];
  const float* c1Wr = (const float*)d_in[5];
  const float* c2Wl = (const float*)d_in[6];
  const float* c2bl = (const float*)d_in[7];
  const float* c2Wr = (const float*)d_in[8];
  const float* clfW = (const float*)d_in[9];
  const float* clfb = (const float*)d_in[10];
  const int* e0 = (const int*)d_in[11];
  const int* e1 = (const int*)d_in[12];
  const int* e2 = (const int*)d_in[13];
  const int* e3 = (const int*)d_in[14];

  const int NA = in_sizes[0] / D128;
  const int NM = in_sizes[1] / D128;
  const int ND = in_sizes[2] / D128;
  const int E = in_sizes[11] / 2;
  float* out = (float*)d_out;

  char* wsb = (char*)d_ws;
  size_t off = 0;
  auto alloc = [&](size_t bytes) -> char* {
    char* p = wsb + off;
    off += (bytes + 511) & ~(size_t)511;
    return p;
  };
  ushort_t* wl1 = (ushort_t*)alloc((size_t)4 * 16384 * 2);
  ushort_t* wr1 = (ushort_t*)alloc((size_t)4 * 16384 * 2);
  ushort_t* wl2 = (ushort_t*)alloc((size_t)4 * 16384 * 2);
  ushort_t* wr2 = (ushort_t*)alloc((size_t)4 * 16384 * 2);
  ushort_t* eapp = (ushort_t*)alloc((size_t)NA * D128 * 2);
  ushort_t* emer = (ushort_t*)alloc((size_t)NM * D128 * 2);
  ushort_t* edev = (ushort_t*)alloc((size_t)ND * D128 * 2);
  ushort_t* h1m = (ushort_t*)alloc((size_t)NM * D128 * 2);  // bf16 raw
  ushort_t* h1d = (ushort_t*)alloc((size_t)ND * D128 * 2);  // bf16 raw
  float* h1a = (float*)alloc((size_t)NA * D128 * 4);        // f32, relu'd
  float* h2a = (float*)alloc((size_t)NA * D128 * 4);        // f32 partial
  ushort_t* agg = (ushort_t*)alloc((size_t)NA * D128 * 2);  // bf16, reused
  int ncnt = NM + NA + ND + NA;
  int nb = (ncnt + 255) / 256;
  int* cnt = (int*)alloc((size_t)ncnt * 4);
  float* inv = (float*)alloc((size_t)ncnt * 4);
  int* ofs = (int*)alloc((size_t)ncnt * 4);
  int* cur = (int*)alloc((size_t)ncnt * 4);
  int* bsum = (int*)alloc((size_t)nb * 4);
  int* bucket = (int*)alloc((size_t)4 * E * 4);
  (void)ws_size;  // ~395 MB

  int b0 = 0, b1 = NM, b2 = NM + NA, b3 = NM + NA + ND;

  const int SMEM = 65536;
  hipFuncSetAttribute((const void*)sage5<1, 0, 1, 0, 0>,
                      hipFuncAttributeMaxDynamicSharedMemorySize, SMEM);
  hipFuncSetAttribute((const void*)sage5<1, 0, 0, 0, 0>,
                      hipFuncAttributeMaxDynamicSharedMemorySize, SMEM);
  hipFuncSetAttribute((const void*)sage5<1, 1, 0, 1, 0>,
                      hipFuncAttributeMaxDynamicSharedMemorySize, SMEM);
  hipFuncSetAttribute((const void*)sage5<0, 0, 0, 0, 0>,
                      hipFuncAttributeMaxDynamicSharedMemorySize, SMEM);
  hipFuncSetAttribute((const void*)sage5<0, 1, 0, 0, 1>,
                      hipFuncAttributeMaxDynamicSharedMemorySize, SMEM);

  // ---- conversions to bf16 (2 launches) ----
  dim3 wg(64, 4);  // 64 blocks x 256 thr x 4 f32 = 65536 f32 per tensor
  cvtW_k<<<wg, 256, 0, stream>>>(c1Wl, c1Wr, c2Wl, c2Wr, wl1, wr1, wl2, wr2);
  int na4 = NA * 32, nm4 = NM * 32, nd4 = ND * 32;
  cvtE_k<<<(na4 + nm4 + nd4 + 255) / 256, 256, 0, stream>>>(
      emb_app, emb_mer, emb_dev, eapp, emer, edev, na4, nm4, nd4);

  // ---- degree counts + CSR build (5 launches) ----
  hipMemsetAsync(cnt, 0, (size_t)ncnt * 4, stream);
  dim3 eg((E + 255) / 256, 4);
  count4_k<<<eg, 256, 0, stream>>>(e0 + E, e1 + E, e2 + E, e3 + E, cnt, E, b0, b1, b2, b3);
  scan1_k<<<nb, 256, 0, stream>>>(cnt, bsum, ncnt);
  scan2_k<<<nb, 256, 0, stream>>>(cnt, bsum, ofs, cur, inv, ncnt);
  fill4_k<<<eg, 256, 0, stream>>>(e0, e1, e2, e3, cur, bucket, E, b0, b1, b2, b3);

  auto wgrid = [](int n) { return (n + 3) / 4; };    // gather: one wave/node
  auto g8 = [](int nt) { return (nt + 7) / 8; };     // sage: 8 waves/block
  int tA = NA / 16, tM = NM / 16, tD = ND / 16;

  // ---- layer 1 ----
  // k0: app -> mer (h1m bf16 raw)
  agg_g4<0><<<wgrid(NM), 256, 0, stream>>>(eapp, ofs + b0, cnt + b0, inv + b0, bucket, agg, NM);
  sage5<1, 0, 1, 0, 0><<<g8(tM), 512, SMEM, stream>>>(agg, emer,
      wl1 + 0 * 16384, wr1 + 0 * 16384, c1bl + 0 * D128, nullptr, nullptr, nullptr, h1m, tM);
  // k2: app -> dev (h1d bf16 raw)
  agg_g4<0><<<wgrid(ND), 256, 0, stream>>>(eapp, ofs + b2, cnt + b2, inv + b2, bucket, agg, ND);
  sage5<1, 0, 1, 0, 0><<<g8(tD), 512, SMEM, stream>>>(agg, edev,
      wl1 + 2 * 16384, wr1 + 2 * 16384, c1bl + 2 * D128, nullptr, nullptr, nullptr, h1d, tD);
  // k1: mer -> app (f32 raw partial)
  agg_g4<0><<<wgrid(NA), 256, 0, stream>>>(emer, ofs + b1, cnt + b1, inv + b1, bucket, agg, NA);
  sage5<1, 0, 0, 0, 0><<<g8(tA), 512, SMEM, stream>>>(agg, eapp,
      wl1 + 1 * 16384, wr1 + 1 * 16384, c1bl + 1 * D128, nullptr, nullptr, nullptr, h1a, tA);
  // k3: dev -> app (add partial, relu, finalize h1a f32)
  agg_g4<0><<<wgrid(NA), 256, 0, stream>>>(edev, ofs + b3, cnt + b3, inv + b3, bucket, agg, NA);
  sage5<1, 1, 0, 1, 0><<<g8(tA), 512, SMEM, stream>>>(agg, eapp,
      wl1 + 3 * 16384, wr1 + 3 * 16384, c1bl + 3 * D128, h1a, nullptr, nullptr, h1a, tA);

  // ---- layer 2 (dst=app only) ----
  // k1: mer -> app; gather relu(h1m) -> f32 raw partial h2a
  agg_g4<1><<<wgrid(NA), 256, 0, stream>>>(h1m, ofs + b1, cnt + b1, inv + b1, bucket, agg, NA);
  sage5<0, 0, 0, 0, 0><<<g8(tA), 512, SMEM, stream>>>(agg, h1a,
      wl2 + 1 * 16384, wr2 + 1 * 16384, c2bl + 1 * D128, nullptr, nullptr, nullptr, h2a, tA);
  // k3: dev -> app; gather relu(h1d); add h2a; fused classifier
  agg_g4<1><<<wgrid(NA), 256, 0, stream>>>(h1d, ofs + b3, cnt + b3, inv + b3, bucket, agg, NA);
  sage5<0, 1, 0, 0, 1><<<g8(tA), 512, SMEM, stream>>>(agg, h1a,
      wl2 + 3 * 16384, wr2 + 3 * 16384, c2bl + 3 * D128, h2a, clfW, clfb, out, tA);
}

// Round 9
// 715.201 us; speedup vs baseline: 2.0422x; 1.1286x over previous
//
#include <hip/hip_runtime.h>
#include <hip/hip_bf16.h>

#define D128 128

typedef __attribute__((ext_vector_type(8))) short bf16x8;
typedef __attribute__((ext_vector_type(4))) float f32x4;
typedef unsigned int uint;
typedef unsigned short ushort_t;

union U4 { uint4 u; bf16x8 h; };
__device__ __forceinline__ bf16x8 as_h(uint4 u) { U4 x; x.u = u; return x.h; }

__device__ __forceinline__ short f2bf(float f) {
  union { float f; unsigned u; } v; v.f = f;
  unsigned r = v.u + 0x7FFFu + ((v.u >> 16) & 1u);  // RNE
  return (short)(r >> 16);
}
__device__ __forceinline__ float bf_lo(uint v) {
  union { uint u; float f; } x; x.u = v << 16; return x.f;
}
__device__ __forceinline__ float bf_hi(uint v) {
  union { uint u; float f; } x; x.u = v & 0xFFFF0000u; return x.f;
}
__device__ __forceinline__ uint pack2(float a, float b) {
  return (uint)(unsigned short)f2bf(a) | ((uint)(unsigned short)f2bf(b) << 16);
}

// ---- fused f32->bf16 conversion: 3 embeddings in one launch ----
__global__ __launch_bounds__(256)
void cvtE_k(const float* __restrict__ ia, const float* __restrict__ im,
            const float* __restrict__ id, ushort_t* __restrict__ oa,
            ushort_t* __restrict__ om, ushort_t* __restrict__ od,
            int na4, int nm4, int nd4) {
  int i = blockIdx.x * 256 + threadIdx.x;
  const float* in; ushort_t* out; int k;
  if (i < na4) { in = ia; out = oa; k = i; }
  else if (i < na4 + nm4) { in = im; out = om; k = i - na4; }
  else if (i < na4 + nm4 + nd4) { in = id; out = od; k = i - na4 - nm4; }
  else return;
  float4 v = ((const float4*)in)[k];
  ushort4 o;
  o.x = (unsigned short)f2bf(v.x); o.y = (unsigned short)f2bf(v.y);
  o.z = (unsigned short)f2bf(v.z); o.w = (unsigned short)f2bf(v.w);
  ((ushort4*)out)[k] = o;
}

// ---- 4 weight tensors in one launch (65536 f32 each = 16384 float4) ----
__global__ __launch_bounds__(256)
void cvtW_k(const float* __restrict__ w0, const float* __restrict__ w1,
            const float* __restrict__ w2, const float* __restrict__ w3,
            ushort_t* __restrict__ o0, ushort_t* __restrict__ o1,
            ushort_t* __restrict__ o2, ushort_t* __restrict__ o3) {
  int y = blockIdx.y;
  const float* in = y == 0 ? w0 : y == 1 ? w1 : y == 2 ? w2 : w3;
  ushort_t* out = y == 0 ? o0 : y == 1 ? o1 : y == 2 ? o2 : o3;
  int i = blockIdx.x * 256 + threadIdx.x;
  if (i >= 16384) return;
  float4 v = ((const float4*)in)[i];
  ushort4 o;
  o.x = (unsigned short)f2bf(v.x); o.y = (unsigned short)f2bf(v.y);
  o.z = (unsigned short)f2bf(v.z); o.w = (unsigned short)f2bf(v.w);
  ((ushort4*)out)[i] = o;
}

// ---- count + per-edge rank (pos) in one atomic pass; pos write coalesced ----
__global__ __launch_bounds__(256)
void poscount4_k(const int* __restrict__ d0, const int* __restrict__ d1,
                 const int* __restrict__ d2, const int* __restrict__ d3,
                 int* __restrict__ cnt, int* __restrict__ pos,
                 int nE, int b0, int b1, int b2, int b3) {
  int i = blockIdx.x * 256 + threadIdx.x;
  if (i >= nE) return;
  int y = blockIdx.y;
  const int* d = y == 0 ? d0 : y == 1 ? d1 : y == 2 ? d2 : d3;
  int base = y == 0 ? b0 : y == 1 ? b1 : y == 2 ? b2 : b3;
  int p = atomicAdd(&cnt[base + d[i]], 1);
  pos[(size_t)y * nE + i] = p;
}

// ---- scan stage 1 ----
__device__ __forceinline__ int wave_incl_scan(int v, int lane) {
#pragma unroll
  for (int off = 1; off < 64; off <<= 1) {
    int y = __shfl_up(v, off);
    if (lane >= off) v += y;
  }
  return v;
}

__global__ __launch_bounds__(256) void scan1_k(const int* __restrict__ cnt,
                                               int* __restrict__ bsum, int n) {
  int b = blockIdx.x, tid = threadIdx.x;
  int i = b * 256 + tid;
  int v = (i < n) ? cnt[i] : 0;
  int lane = tid & 63, wid = tid >> 6;
  __shared__ int ws[4];
  int s = wave_incl_scan(v, lane);
  if (lane == 63) ws[wid] = s;
  __syncthreads();
  if (tid == 0) bsum[b] = ws[0] + ws[1] + ws[2] + ws[3];
}

// ---- scan stage 2 (+ inv fold) ----
__global__ __launch_bounds__(256) void scan2_k(const int* __restrict__ cnt,
                                               const int* __restrict__ bsum,
                                               int* __restrict__ ofs,
                                               float* __restrict__ inv, int n) {
  int b = blockIdx.x, tid = threadIdx.x;
  int lane = tid & 63, wid = tid >> 6;
  __shared__ int wsA[4], wsB[4];
  int p = 0;
  for (int j = tid; j < b; j += 256) p += bsum[j];
#pragma unroll
  for (int off = 32; off; off >>= 1) p += __shfl_xor(p, off);
  if (lane == 0) wsA[wid] = p;
  __syncthreads();
  int base = wsA[0] + wsA[1] + wsA[2] + wsA[3];
  int i = b * 256 + tid;
  int v = (i < n) ? cnt[i] : 0;
  int s = wave_incl_scan(v, lane);
  if (lane == 63) wsB[wid] = s;
  __syncthreads();
  int woff = 0;
  for (int w = 0; w < wid; w++) woff += wsB[w];
  int excl = base + woff + s - v;
  if (i < n) {
    ofs[i] = excl;
    inv[i] = 1.0f / (float)(v > 1 ? v : 1);
  }
}

// ---- reorder: bucket fill with NO atomics (uses precomputed pos) ----
__global__ __launch_bounds__(256)
void reorder4_k(const int* __restrict__ e0, const int* __restrict__ e1,
                const int* __restrict__ e2, const int* __restrict__ e3,
                const int* __restrict__ ofs, const int* __restrict__ pos,
                int* __restrict__ bucket,
                int nE, int b0, int b1, int b2, int b3) {
  int i = blockIdx.x * 256 + threadIdx.x;
  if (i >= nE) return;
  int y = blockIdx.y;
  const int* e = y == 0 ? e0 : y == 1 ? e1 : y == 2 ? e2 : e3;
  int base = y == 0 ? b0 : y == 1 ? b1 : y == 2 ? b2 : b3;
  int s = e[i];
  int d = e[nE + i];
  int p = pos[(size_t)y * nE + i];
  bucket[ofs[base + d] + p] = s;
}

// ---- dual CSR gather-mean: blockIdx.y selects independent job A or B ----
struct GJob {
  const ushort_t* x;
  const int* ofs;
  const int* cnt;
  const float* inv;
  ushort_t* agg;
  int n;
};

template <int RELU>
__global__ __launch_bounds__(256)
void agg2_k(GJob A, GJob B, const int* __restrict__ bucket) {
  const GJob& J = blockIdx.y ? B : A;
  int w = (int)(((size_t)blockIdx.x * 256 + threadIdx.x) >> 6);
  int lane = threadIdx.x & 63;
  if (w >= J.n) return;
  int g = lane >> 4, sl = lane & 15;
  int beg = J.ofs[w], c = J.cnt[w];
  float iv = J.inv[w];
  const ushort_t* xsrc = J.x;
  float a[8] = {0.f, 0.f, 0.f, 0.f, 0.f, 0.f, 0.f, 0.f};

  auto accum = [&](uint4 v) {
    float x0 = bf_lo(v.x), x1 = bf_hi(v.x), x2 = bf_lo(v.y), x3 = bf_hi(v.y);
    float x4 = bf_lo(v.z), x5 = bf_hi(v.z), x6 = bf_lo(v.w), x7 = bf_hi(v.w);
    if (RELU) {
      x0 = fmaxf(x0, 0.f); x1 = fmaxf(x1, 0.f); x2 = fmaxf(x2, 0.f); x3 = fmaxf(x3, 0.f);
      x4 = fmaxf(x4, 0.f); x5 = fmaxf(x5, 0.f); x6 = fmaxf(x6, 0.f); x7 = fmaxf(x7, 0.f);
    }
    a[0] += x0; a[1] += x1; a[2] += x2; a[3] += x3;
    a[4] += x4; a[5] += x5; a[6] += x6; a[7] += x7;
  };

  int j = g;
  for (; j + 4 < c; j += 8) {
    int s0 = bucket[beg + j];
    int s1 = bucket[beg + j + 4];
    uint4 v0 = *(const uint4*)(xsrc + (size_t)s0 * D128 + sl * 8);
    uint4 v1 = *(const uint4*)(xsrc + (size_t)s1 * D128 + sl * 8);
    accum(v0); accum(v1);
  }
  if (j < c) {
    int s0 = bucket[beg + j];
    uint4 v0 = *(const uint4*)(xsrc + (size_t)s0 * D128 + sl * 8);
    accum(v0);
  }

#pragma unroll
  for (int k = 0; k < 8; k++) {
    a[k] += __shfl_xor(a[k], 16);
    a[k] += __shfl_xor(a[k], 32);
  }
  if (g == 0) {
    uint4 o;
    o.x = pack2(a[0] * iv, a[1] * iv);
    o.y = pack2(a[2] * iv, a[3] * iv);
    o.z = pack2(a[4] * iv, a[5] * iv);
    o.w = pack2(a[6] * iv, a[7] * iv);
    *(uint4*)(J.agg + (size_t)w * D128 + sl * 8) = o;
  }
}

// ---- fused SAGE transform (single edge type), LDS-staged weights ----
//  (unchanged -- proven since R5)
template <int XBF, int ACC, int BFOUT, int OUTRELU, int CLF>
__global__ __launch_bounds__(512)
void sage5(const ushort_t* __restrict__ agg, const void* __restrict__ xv,
           const ushort_t* __restrict__ wl, const ushort_t* __restrict__ wr,
           const float* __restrict__ bias, const float* __restrict__ prevf,
           const float* __restrict__ clfW, const float* __restrict__ clfb,
           void* __restrict__ outv, int ntiles) {
  extern __shared__ char smem[];  // 65536 = 2 x (128x128 bf16) swizzled
  const int tid = threadIdx.x;

  for (int c = tid; c < 4096; c += 512) {
    int m = c >> 11, cc = c & 2047;
    int row = cc >> 4, slot = cc & 15;
    const ushort_t* W = m ? wr : wl;
    uint4 v = *((const uint4*)W + cc);
    *(uint4*)(smem + m * 32768 + row * 256 + ((slot ^ (row & 15)) << 4)) = v;
  }
  __syncthreads();

  int wid = tid >> 6, lane = tid & 63;
  int r = lane & 15, kh = lane >> 4;
  int tile = blockIdx.x * 8 + wid;
  if (tile >= ntiles) return;
  size_t n0 = (size_t)tile * 16;

  const ushort_t* ap = agg + (n0 + r) * D128 + kh * 8;
  uint4 A[4];
  bf16x8 XF[4];
#pragma unroll
  for (int kk = 0; kk < 4; kk++) A[kk] = *(const uint4*)(ap + kk * 32);
  if (XBF) {
    const ushort_t* xp = (const ushort_t*)xv + (n0 + r) * D128 + kh * 8;
#pragma unroll
    for (int kk = 0; kk < 4; kk++) XF[kk] = as_h(*(const uint4*)(xp + kk * 32));
  } else {
    const float* xp = (const float*)xv + (n0 + r) * D128 + kh * 8;
#pragma unroll
    for (int kk = 0; kk < 4; kk++) {
      f32x4 x0 = *(const f32x4*)(xp + kk * 32);
      f32x4 x1 = *(const f32x4*)(xp + kk * 32 + 4);
#pragma unroll
      for (int j = 0; j < 4; j++) {
        XF[kk][j] = f2bf(x0[j]);
        XF[kk][j + 4] = f2bf(x1[j]);
      }
    }
  }

  f32x4 acc[8];
#pragma unroll
  for (int t = 0; t < 8; t++) acc[t] = (f32x4){0.f, 0.f, 0.f, 0.f};

#pragma unroll
  for (int kk = 0; kk < 4; kk++) {
    int so = (((kk << 2) + kh) ^ r) << 4;
    bf16x8 af = as_h(A[kk]);
    bf16x8 xf = XF[kk];
#pragma unroll
    for (int t = 0; t < 8; t++) {
      const char* p = smem + t * 4096 + r * 256 + so;
      bf16x8 bwl = *(const bf16x8*)(p);
      bf16x8 bwr = *(const bf16x8*)(p + 32768);
      acc[t] = __builtin_amdgcn_mfma_f32_16x16x32_bf16(af, bwl, acc[t], 0, 0, 0);
      acc[t] = __builtin_amdgcn_mfma_f32_16x16x32_bf16(xf, bwr, acc[t], 0, 0, 0);
    }
  }

  float s[4] = {0.f, 0.f, 0.f, 0.f};
#pragma unroll
  for (int t = 0; t < 8; t++) {
    float bv = bias[t * 16 + r];
#pragma unroll
    for (int q = 0; q < 4; q++) {
      float c = acc[t][q] + bv;
      acc[t][q] = c;
      s[q] += c * c;
    }
  }
#pragma unroll
  for (int off = 1; off < 16; off <<= 1) {
#pragma unroll
    for (int q = 0; q < 4; q++) s[q] += __shfl_xor(s[q], off);
  }
  float rn[4];
#pragma unroll
  for (int q = 0; q < 4; q++) rn[q] = 1.0f / fmaxf(sqrtf(s[q]), 1e-12f);

  if (CLF) {
    float w0[8], w1[8];
#pragma unroll
    for (int t = 0; t < 8; t++) {
      w0[t] = clfW[t * 16 + r];
      w1[t] = clfW[D128 + t * 16 + r];
    }
    float p0[4] = {0.f, 0.f, 0.f, 0.f}, p1[4] = {0.f, 0.f, 0.f, 0.f};
#pragma unroll
    for (int t = 0; t < 8; t++) {
#pragma unroll
      for (int q = 0; q < 4; q++) {
        float val = acc[t][q] * rn[q];
        if (ACC) {
          size_t node = n0 + kh * 4 + q;
          val += prevf[node * D128 + t * 16 + r];
        }
        p0[q] += val * w0[t];
        p1[q] += val * w1[t];
      }
    }
#pragma unroll
    for (int off = 1; off < 16; off <<= 1) {
#pragma unroll
      for (int q = 0; q < 4; q++) {
        p0[q] += __shfl_xor(p0[q], off);
        p1[q] += __shfl_xor(p1[q], off);
      }
    }
    if (r == 0) {
      float cb0 = clfb[0], cb1 = clfb[1];
#pragma unroll
      for (int q = 0; q < 4; q++) {
        size_t node = n0 + kh * 4 + q;
        float2 o; o.x = p0[q] + cb0; o.y = p1[q] + cb1;
        *(float2*)((float*)outv + node * 2) = o;
      }
    }
  } else {
#pragma unroll
    for (int t = 0; t < 8; t++) {
#pragma unroll
      for (int q = 0; q < 4; q++) {
        float val = acc[t][q] * rn[q];
        size_t node = n0 + kh * 4 + q;
        if (ACC) val += prevf[node * D128 + t * 16 + r];
        if (OUTRELU) val = fmaxf(val, 0.f);
        if (BFOUT) {
          float pv = __shfl_xor(val, 1);
          if ((r & 1) == 0)
            *(uint*)((ushort_t*)outv + node * D128 + t * 16 + r) = pack2(val, pv);
        } else {
          ((float*)outv)[node * D128 + t * 16 + r] = val;
        }
      }
    }
  }
}

extern "C" void kernel_launch(void* const* d_in, const int* in_sizes, int n_in,
                              void* d_out, int out_size, void* d_ws, size_t ws_size,
                              hipStream_t stream) {
  const float* emb_app = (const float*)d_in[0];
  const float* emb_mer = (const float*)d_in[1];
  const float* emb_dev = (const float*)d_in[2];
  const float* c1Wl = (const float*)d_in[3];
  const float* c1bl = (const float*)d_in[4];
  const float* c1Wr = (const float*)d_in[5];
  const float* c2Wl = (const float*)d_in[6];
  const float* c2bl = (const float*)d_in[7];
  const float* c2Wr = (const float*)d_in[8];
  const float* clfW = (const float*)d_in[9];
  const float* clfb = (const float*)d_in[10];
  const int* e0 = (const int*)d_in[11];
  const int* e1 = (const int*)d_in[12];
  const int* e2 = (const int*)d_in[13];
  const int* e3 = (const int*)d_in[14];

  const int NA = in_sizes[0] / D128;
  const int NM = in_sizes[1] / D128;
  const int ND = in_sizes[2] / D128;
  const int E = in_sizes[11] / 2;
  float* out = (float*)d_out;

  char* wsb = (char*)d_ws;
  size_t off = 0;
  auto alloc = [&](size_t bytes) -> char* {
    char* p = wsb + off;
    off += (bytes + 511) & ~(size_t)511;
    return p;
  };
  ushort_t* wl1 = (ushort_t*)alloc((size_t)4 * 16384 * 2);
  ushort_t* wr1 = (ushort_t*)alloc((size_t)4 * 16384 * 2);
  ushort_t* wl2 = (ushort_t*)alloc((size_t)4 * 16384 * 2);
  ushort_t* wr2 = (ushort_t*)alloc((size_t)4 * 16384 * 2);

  // ---- overlay region: L1 = [emer | edev | eapp] bf16, L2 = h2a f32 ----
  // (embeddings dead after layer 1; h2a live only in layer 2; cvtE rewrites
  //  the region at the start of every replay -> graph-deterministic)
  size_t embBytes = ((size_t)NM + ND + NA) * D128 * 2;   // 89.6 MB
  size_t h2aBytes = (size_t)NA * D128 * 4;               // 102.4 MB
  char* big = alloc(embBytes > h2aBytes ? embBytes : h2aBytes);
  ushort_t* emer = (ushort_t*)big;
  ushort_t* edev = emer + (size_t)NM * D128;
  ushort_t* eapp = edev + (size_t)ND * D128;
  float* h2a = (float*)big;

  ushort_t* h1m = (ushort_t*)alloc((size_t)NM * D128 * 2);  // bf16 raw
  ushort_t* h1d = (ushort_t*)alloc((size_t)ND * D128 * 2);  // bf16 raw
  float* h1a = (float*)alloc((size_t)NA * D128 * 4);        // f32, relu'd
  ushort_t* aggA = (ushort_t*)alloc((size_t)NA * D128 * 2); // bf16
  ushort_t* aggB = (ushort_t*)alloc((size_t)NA * D128 * 2); // bf16
  int ncnt = NM + NA + ND + NA;
  int nb = (ncnt + 255) / 256;
  int* cnt = (int*)alloc((size_t)ncnt * 4);
  float* inv = (float*)alloc((size_t)ncnt * 4);
  int* ofs = (int*)alloc((size_t)ncnt * 4);
  int* bsum = (int*)alloc((size_t)nb * 4);
  int* pos = (int*)alloc((size_t)4 * E * 4);
  int* bucket = (int*)alloc((size_t)4 * E * 4);
  (void)ws_size;  // ~369 MB total (< R7's proven ~402 MB)

  int b0 = 0, b1 = NM, b2 = NM + NA, b3 = NM + NA + ND;

  const int SMEM = 65536;
  hipFuncSetAttribute((const void*)sage5<1, 0, 1, 0, 0>,
                      hipFuncAttributeMaxDynamicSharedMemorySize, SMEM);
  hipFuncSetAttribute((const void*)sage5<1, 0, 0, 0, 0>,
                      hipFuncAttributeMaxDynamicSharedMemorySize, SMEM);
  hipFuncSetAttribute((const void*)sage5<1, 1, 0, 1, 0>,
                      hipFuncAttributeMaxDynamicSharedMemorySize, SMEM);
  hipFuncSetAttribute((const void*)sage5<0, 0, 0, 0, 0>,
                      hipFuncAttributeMaxDynamicSharedMemorySize, SMEM);
  hipFuncSetAttribute((const void*)sage5<0, 1, 0, 0, 1>,
                      hipFuncAttributeMaxDynamicSharedMemorySize, SMEM);

  // ---- conversions to bf16 (2 launches) ----
  dim3 wg(64, 4);
  cvtW_k<<<wg, 256, 0, stream>>>(c1Wl, c1Wr, c2Wl, c2Wr, wl1, wr1, wl2, wr2);
  int na4 = NA * 32, nm4 = NM * 32, nd4 = ND * 32;
  cvtE_k<<<(na4 + nm4 + nd4 + 255) / 256, 256, 0, stream>>>(
      emb_app, emb_mer, emb_dev, eapp, emer, edev, na4, nm4, nd4);

  // ---- CSR build: 1 atomic pass + scan + atomic-free reorder ----
  hipMemsetAsync(cnt, 0, (size_t)ncnt * 4, stream);
  dim3 eg((E + 255) / 256, 4);
  poscount4_k<<<eg, 256, 0, stream>>>(e0 + E, e1 + E, e2 + E, e3 + E,
                                      cnt, pos, E, b0, b1, b2, b3);
  scan1_k<<<nb, 256, 0, stream>>>(cnt, bsum, ncnt);
  scan2_k<<<nb, 256, 0, stream>>>(cnt, bsum, ofs, inv, ncnt);
  reorder4_k<<<eg, 256, 0, stream>>>(e0, e1, e2, e3, ofs, pos, bucket,
                                     E, b0, b1, b2, b3);

  auto wgrid = [](int n) { return (n + 3) / 4; };    // gather: one wave/node
  auto g8 = [](int nt) { return (nt + 7) / 8; };     // sage: 8 waves/block
  int tA = NA / 16, tM = NM / 16, tD = ND / 16;

  auto J = [&](const ushort_t* x, int b, ushort_t* a, int n) {
    GJob j; j.x = x; j.ofs = ofs + b; j.cnt = cnt + b; j.inv = inv + b;
    j.agg = a; j.n = n; return j;
  };

  // ---- layer 1 ----
  // gathers k0 (app->mer) and k2 (app->dev) overlap in one launch
  {
    dim3 gg(wgrid(NM > ND ? NM : ND), 2);
    agg2_k<0><<<gg, 256, 0, stream>>>(J(eapp, b0, aggA, NM), J(eapp, b2, aggB, ND), bucket);
  }
  sage5<1, 0, 1, 0, 0><<<g8(tM), 512, SMEM, stream>>>(aggA, emer,
      wl1 + 0 * 16384, wr1 + 0 * 16384, c1bl + 0 * D128, nullptr, nullptr, nullptr, h1m, tM);
  sage5<1, 0, 1, 0, 0><<<g8(tD), 512, SMEM, stream>>>(aggB, edev,
      wl1 + 2 * 16384, wr1 + 2 * 16384, c1bl + 2 * D128, nullptr, nullptr, nullptr, h1d, tD);
  // gathers k1 (mer->app) and k3 (dev->app) overlap
  {
    dim3 gg(wgrid(NA), 2);
    agg2_k<0><<<gg, 256, 0, stream>>>(J(emer, b1, aggA, NA), J(edev, b3, aggB, NA), bucket);
  }
  sage5<1, 0, 0, 0, 0><<<g8(tA), 512, SMEM, stream>>>(aggA, eapp,
      wl1 + 1 * 16384, wr1 + 1 * 16384, c1bl + 1 * D128, nullptr, nullptr, nullptr, h1a, tA);
  sage5<1, 1, 0, 1, 0><<<g8(tA), 512, SMEM, stream>>>(aggB, eapp,
      wl1 + 3 * 16384, wr1 + 3 * 16384, c1bl + 3 * D128, h1a, nullptr, nullptr, h1a, tA);

  // ---- layer 2 (dst=app only; embeddings in `big` now dead -> h2a reuses it) ----
  {
    dim3 gg(wgrid(NA), 2);
    agg2_k<1><<<gg, 256, 0, stream>>>(J(h1m, b1, aggA, NA), J(h1d, b3, aggB, NA), bucket);
  }
  sage5<0, 0, 0, 0, 0><<<g8(tA), 512, SMEM, stream>>>(aggA, h1a,
      wl2 + 1 * 16384, wr2 + 1 * 16384, c2bl + 1 * D128, nullptr, nullptr, nullptr, h2a, tA);
  sage5<0, 1, 0, 0, 1><<<g8(tA), 512, SMEM, stream>>>(aggB, h1a,
      wl2 + 3 * 16384, wr2 + 3 * 16384, c2bl + 3 * D128, h2a, clfW, clfb, out, tA);
}